// Round 10
// baseline (84.735 us; speedup 1.0000x reference)
//
#include <hip/hip_runtime.h>
#include <math.h>

#define Q_TOTAL 21760
#define QB 16        // queries per sampling block
#define HEAD_IMG_BYTES 1392640   // 21760 * 32 * 2  (one head's transposed image, f16)

typedef _Float16     f16;
typedef short        s16x8 __attribute__((ext_vector_type(8)));
typedef f16          f16x8 __attribute__((ext_vector_type(8)));
typedef f16          f16x4 __attribute__((ext_vector_type(4)));
typedef f16          f16x2 __attribute__((ext_vector_type(2)));
typedef __bf16       bfv8  __attribute__((ext_vector_type(8)));
typedef float        f32x4 __attribute__((ext_vector_type(4)));
typedef float        f32x2 __attribute__((ext_vector_type(2)));
typedef unsigned int u32x4 __attribute__((ext_vector_type(4)));
typedef unsigned int u32x2 __attribute__((ext_vector_type(2)));

// pack 8 floats -> 8 bf16 (RNE; compiler emits v_cvt_pk_bf16_f32)
__device__ __forceinline__ s16x8 pack8(float4 a, float4 b) {
    bfv8 t;
    t[0] = (__bf16)a.x; t[1] = (__bf16)a.y; t[2] = (__bf16)a.z; t[3] = (__bf16)a.w;
    t[4] = (__bf16)b.x; t[5] = (__bf16)b.y; t[6] = (__bf16)b.z; t[7] = (__bf16)b.w;
    return __builtin_bit_cast(s16x8, t);
}

// ---------------------------------------------------------------------------
// Fused projection GEMM, BM=128, BN=128, BK=32, 256 threads = 4 waves (2x2).
// grid (170, 5): slab 0-1 = value proj (A=input_flatten, W_val) -> value_t
//                slab 2-4 = off/attn  (A=query, W_off/W_attn)   -> offattn
// Weights staged f32 -> bf16 in-kernel (no cvt pass). LDS XOR-swizzled.
// ---------------------------------------------------------------------------
__global__ __launch_bounds__(256) void gemm_fused(
    const float* __restrict__ input_flatten,
    const float* __restrict__ query,
    const float* __restrict__ W_val,  const float* __restrict__ b_val,
    const float* __restrict__ W_off,  const float* __restrict__ b_off,
    const float* __restrict__ W_attn, const float* __restrict__ b_attn,
    f16* __restrict__ value_t, f16* __restrict__ offattn)
{
    constexpr int K = 256;
    __shared__ unsigned short As[128 * 32];
    __shared__ unsigned short Bs[128 * 32];

    const int tid  = threadIdx.x;
    const int lane = tid & 63;
    const int wv   = tid >> 6;
    const int wr   = wv >> 1, wc = wv & 1;
    const int rowBase = blockIdx.x * 128;
    const int slab = blockIdx.y;

    const float* A32; const float* Wf; const float* bias;
    if (slab < 2)       { A32 = input_flatten; Wf = W_val + slab * 32768; bias = b_val + slab * 128; }
    else if (slab == 2) { A32 = query;         Wf = W_off;                bias = b_off; }
    else if (slab == 3) { A32 = query;         Wf = W_off + 32768;       bias = b_off + 128; }
    else                { A32 = query;         Wf = W_attn;               bias = b_attn; }

    const int sr  = tid >> 1;           // staging row 0..127
    const int sk0 = (tid & 1) * 16;     // elem offset 0 or 16
    const int sby = (tid & 1) * 32;     // byte slot base

    f32x4 acc[4][4];
#pragma unroll
    for (int i = 0; i < 4; i++)
#pragma unroll
        for (int j = 0; j < 4; j++) acc[i][j] = (f32x4){0.f, 0.f, 0.f, 0.f};

    const float* Ap = A32 + (size_t)(rowBase + sr) * K + sk0;
    const float* Wp = Wf + (size_t)sr * K + sk0;

    for (int kt = 0; kt < K; kt += 32) {
        s16x8 a0 = pack8(*(const float4*)(Ap + kt),     *(const float4*)(Ap + kt + 4));
        s16x8 a1 = pack8(*(const float4*)(Ap + kt + 8), *(const float4*)(Ap + kt + 12));
        s16x8 b0 = pack8(*(const float4*)(Wp + kt),     *(const float4*)(Wp + kt + 4));
        s16x8 b1 = pack8(*(const float4*)(Wp + kt + 8), *(const float4*)(Wp + kt + 12));
        __syncthreads();
        *(s16x8*)((char*)As + ((sr * 64 + sby)      ^ ((sr & 7) << 4))) = a0;
        *(s16x8*)((char*)As + ((sr * 64 + sby + 16) ^ ((sr & 7) << 4))) = a1;
        *(s16x8*)((char*)Bs + ((sr * 64 + sby)      ^ ((sr & 7) << 4))) = b0;
        *(s16x8*)((char*)Bs + ((sr * 64 + sby + 16) ^ ((sr & 7) << 4))) = b1;
        __syncthreads();
        s16x8 af[4], bf[4];
#pragma unroll
        for (int mi = 0; mi < 4; mi++) {
            const int row = wr * 64 + mi * 16 + (lane & 15);
            af[mi] = *(const s16x8*)((char*)As + ((row * 64 + (lane >> 4) * 16) ^ ((row & 7) << 4)));
        }
#pragma unroll
        for (int ni = 0; ni < 4; ni++) {
            const int row = wc * 64 + ni * 16 + (lane & 15);
            bf[ni] = *(const s16x8*)((char*)Bs + ((row * 64 + (lane >> 4) * 16) ^ ((row & 7) << 4)));
        }
#pragma unroll
        for (int ni = 0; ni < 4; ni++)
#pragma unroll
            for (int mi = 0; mi < 4; mi++)
                acc[mi][ni] = __builtin_amdgcn_mfma_f32_16x16x32_bf16(af[mi], bf[ni], acc[mi][ni], 0, 0, 0);
    }

#pragma unroll
    for (int ni = 0; ni < 4; ni++) {
        const int localcol = wc * 64 + ni * 16 + (lane & 15);
        const float bv = bias[localcol];
#pragma unroll
        for (int mi = 0; mi < 4; mi++) {
            const int r0 = rowBase + wr * 64 + mi * 16 + (lane >> 4) * 4;
#pragma unroll
            for (int j = 0; j < 4; j++) {
                const float v = acc[mi][ni][j] + bv;
                const int row = r0 + j;
                if (slab < 2) {
                    const int col = slab * 128 + localcol;
                    value_t[((size_t)(col >> 5) * Q_TOTAL + row) * 32 + (col & 31)] = (f16)v;
                } else {
                    const int col = (slab - 2) * 128 + localcol;
                    offattn[(size_t)row * 384 + col] = (f16)v;
                }
            }
        }
    }
}

// ---------------------------------------------------------------------------
// Output GEMM: out[21760][256] f32 = sampled(bf16) @ W_out^T + b_out.
// Same 128x128 tile; W_out staged f32 -> bf16 in-kernel. grid (170, 2).
// ---------------------------------------------------------------------------
__global__ __launch_bounds__(256) void gemm_out(
    const unsigned short* __restrict__ A16,      // sampled bf16 [Q][256]
    const float* __restrict__ Wf,                // W_out f32 [256][256]
    const float* __restrict__ bias,              // b_out
    float* __restrict__ C)
{
    constexpr int K = 256;
    __shared__ unsigned short As[128 * 32];
    __shared__ unsigned short Bs[128 * 32];

    const int tid  = threadIdx.x;
    const int lane = tid & 63;
    const int wv   = tid >> 6;
    const int wr   = wv >> 1, wc = wv & 1;
    const int rowBase = blockIdx.x * 128;
    const int colBase = blockIdx.y * 128;

    const int sr  = tid >> 1;
    const int sk0 = (tid & 1) * 16;
    const int sby = (tid & 1) * 32;

    f32x4 acc[4][4];
#pragma unroll
    for (int i = 0; i < 4; i++)
#pragma unroll
        for (int j = 0; j < 4; j++) acc[i][j] = (f32x4){0.f, 0.f, 0.f, 0.f};

    const unsigned short* Ap = A16 + (size_t)(rowBase + sr) * K + sk0;
    const float* Wp = Wf + (size_t)(colBase + sr) * K + sk0;

    for (int kt = 0; kt < K; kt += 32) {
        s16x8 a0 = *(const s16x8*)(Ap + kt);
        s16x8 a1 = *(const s16x8*)(Ap + kt + 8);
        s16x8 b0 = pack8(*(const float4*)(Wp + kt),     *(const float4*)(Wp + kt + 4));
        s16x8 b1 = pack8(*(const float4*)(Wp + kt + 8), *(const float4*)(Wp + kt + 12));
        __syncthreads();
        *(s16x8*)((char*)As + ((sr * 64 + sby)      ^ ((sr & 7) << 4))) = a0;
        *(s16x8*)((char*)As + ((sr * 64 + sby + 16) ^ ((sr & 7) << 4))) = a1;
        *(s16x8*)((char*)Bs + ((sr * 64 + sby)      ^ ((sr & 7) << 4))) = b0;
        *(s16x8*)((char*)Bs + ((sr * 64 + sby + 16) ^ ((sr & 7) << 4))) = b1;
        __syncthreads();
        s16x8 af[4], bf[4];
#pragma unroll
        for (int mi = 0; mi < 4; mi++) {
            const int row = wr * 64 + mi * 16 + (lane & 15);
            af[mi] = *(const s16x8*)((char*)As + ((row * 64 + (lane >> 4) * 16) ^ ((row & 7) << 4)));
        }
#pragma unroll
        for (int ni = 0; ni < 4; ni++) {
            const int row = wc * 64 + ni * 16 + (lane & 15);
            bf[ni] = *(const s16x8*)((char*)Bs + ((row * 64 + (lane >> 4) * 16) ^ ((row & 7) << 4)));
        }
#pragma unroll
        for (int ni = 0; ni < 4; ni++)
#pragma unroll
            for (int mi = 0; mi < 4; mi++)
                acc[mi][ni] = __builtin_amdgcn_mfma_f32_16x16x32_bf16(af[mi], bf[ni], acc[mi][ni], 0, 0, 0);
    }

#pragma unroll
    for (int ni = 0; ni < 4; ni++) {
        const int col = colBase + wc * 64 + ni * 16 + (lane & 15);
        const float bv = bias[col];
#pragma unroll
        for (int mi = 0; mi < 4; mi++) {
            const int r0 = rowBase + wr * 64 + mi * 16 + (lane >> 4) * 4;
#pragma unroll
            for (int j = 0; j < 4; j++)
                C[(size_t)(r0 + j) * 256 + col] = acc[mi][ni][j] + bv;
        }
    }
}

// ---------------------------------------------------------------------------
// Sampling: block = 16 queries x 2 heads (256 threads).  [unchanged from r9]
// bid = qtile*4 + headpair -> each XCD touches only its 2-head value slice
// (2.78 MB < 4 MB L2) in the transposed f16 layout.
// Phase 1: softmax over 8-lane group; per point and per x-corner writes a
// pre-folded rec {o0+xc*64, o1+xc*64, f32(a*wy0*wx), f32(a*wy1*wx)} into LDS.
// Phase 2: two halves of 8 points; read offsets, issue 16 global loads,
// consume with v_fma_mix_f32; xor(4) reduce combines corners.
// ---------------------------------------------------------------------------
__global__ __launch_bounds__(256) void sample_kernel(
    const f16* __restrict__ value_t,             // [8][Q][32] f16
    const f16* __restrict__ offattn,             // [Q][384] f16
    const float* __restrict__ refpts,            // [Q][4][2] f32
    unsigned short* __restrict__ sampled)        // [Q][256] bf16
{
    __shared__ __attribute__((aligned(16))) unsigned s_iw[32 * 132];

    const int tid   = threadIdx.x;
    const int qt    = blockIdx.x >> 2;
    const int hp    = blockIdx.x & 3;
    const int qbase = qt * QB;

    // ---------------- phase 1 ----------------
    {
        const int q  = tid >> 4;
        const int h  = (tid >> 3) & 1;
        const int l  = (tid >> 1) & 3;
        const int ph = tid & 1;
        const int H  = hp * 2 + h;
        const int g  = tid >> 3;         // q*2 + h
        const f16* oa = offattn + (size_t)(qbase + q) * 384;

        f16x2 lgh = *(const f16x2*)(oa + 256 + H * 16 + l * 4 + ph * 2);
        const float lg0 = (float)lgh[0], lg1 = (float)lgh[1];
        float m = fmaxf(lg0, lg1);
        m = fmaxf(m, __shfl_xor(m, 1));
        m = fmaxf(m, __shfl_xor(m, 2));
        m = fmaxf(m, __shfl_xor(m, 4));
        float e0 = __expf(lg0 - m), e1 = __expf(lg1 - m);
        float s = e0 + e1;
        s += __shfl_xor(s, 1);
        s += __shfl_xor(s, 2);
        s += __shfl_xor(s, 4);
        const float inv = 1.f / s;
        const float aw2[2] = {e0 * inv, e1 * inv};

        f16x4 offh = *(const f16x4*)(oa + H * 32 + l * 8 + ph * 4);
        f32x2 rp = *(const f32x2*)(refpts + (size_t)(qbase + q) * 8 + l * 2);

        const int   SZ[4] = {128, 64, 32, 16};
        const int   ST[4] = {0, 16384, 20480, 21504};
        const int   W_ = SZ[l], START = ST[l];
        const float S = (float)W_;

        unsigned* dst = &s_iw[g * 132 + (l * 4 + ph * 2) * 8];
#pragma unroll
        for (int c = 0; c < 2; c++) {
            const float ox = (float)offh[c * 2], oy = (float)offh[c * 2 + 1];
            const float a = aw2[c];
            const float gx = fmaf(rp[0], S, ox) - 0.5f;
            const float gy = fmaf(rp[1], S, oy) - 0.5f;
            const float x0f = floorf(gx), y0f = floorf(gy);
            const float lx = gx - x0f, ly = gy - y0f;
            const int x0 = (int)x0f, y0 = (int)y0f;
            // x pair, clamped to [0, W-2]; shift weights to match clamp
            const int xs  = min(max(x0, 0), W_ - 2);
            const int sft = xs - x0;
            const float wx0 = (x0 >= 0 && x0 < W_) ? (1.f - lx) : 0.f;
            const float wx1 = (x0 + 1 >= 0 && x0 + 1 < W_) ? lx : 0.f;
            const float wxA = (sft == 0) ? wx0 : ((sft == 1) ? wx1 : 0.f);
            const float wxB = (sft == 0) ? wx1 : ((sft == -1) ? wx0 : 0.f);
            // y rows independent: clamp address, zero weight
            const int y1 = y0 + 1;
            const int y0c = min(max(y0, 0), W_ - 1);
            const int y1c = min(max(y1, 0), W_ - 1);
            const float wy0a = (((y0 >= 0) && (y0 < W_)) ? (1.f - ly) : 0.f) * a;
            const float wy1a = (((y1 >= 0) && (y1 < W_)) ? ly : 0.f) * a;
            const unsigned o0 = (unsigned)((START + y0c * W_ + xs) * 64);
            const unsigned o1 = (unsigned)((START + y1c * W_ + xs) * 64);
            u32x4 r0, r1;
            r0[0] = o0;      r0[1] = o1;
            r0[2] = __float_as_uint(wy0a * wxA);
            r0[3] = __float_as_uint(wy1a * wxA);
            r1[0] = o0 + 64; r1[1] = o1 + 64;
            r1[2] = __float_as_uint(wy0a * wxB);
            r1[3] = __float_as_uint(wy1a * wxB);
            *(u32x4*)(dst + c * 8)     = r0;
            *(u32x4*)(dst + c * 8 + 4) = r1;
        }
    }
    __syncthreads();

    // ---------------- phase 2 ----------------
    {
        const int d8 = tid & 3;
        const int xc = (tid >> 2) & 1;
        const int g  = tid >> 3;          // q*2 + h
        const int q  = g >> 1;
        const int h  = g & 1;
        const int H  = hp * 2 + h;
        const unsigned vbase = (unsigned)(H * HEAD_IMG_BYTES) + (unsigned)(d8 * 16);
        const char* vt = (const char*)value_t;
        const unsigned* iw = &s_iw[g * 132 + xc * 4];

        float acc[8] = {0.f, 0.f, 0.f, 0.f, 0.f, 0.f, 0.f, 0.f};
#pragma unroll
        for (int half = 0; half < 2; half++) {
            u32x2 off[8];
#pragma unroll
            for (int p = 0; p < 8; p++)
                off[p] = *(const u32x2*)(iw + (half * 8 + p) * 8);
            f16x8 v0[8], v1[8];
#pragma unroll
            for (int p = 0; p < 8; p++) {
                v0[p] = *(const f16x8*)(vt + (size_t)(vbase + off[p][0]));
                v1[p] = *(const f16x8*)(vt + (size_t)(vbase + off[p][1]));
            }
#pragma unroll
            for (int p = 0; p < 8; p++) {
                const f32x2 w = *(const f32x2*)(iw + (half * 8 + p) * 8 + 2);
#pragma unroll
                for (int r = 0; r < 8; r++) {
                    acc[r] = fmaf((float)v0[p][r], w[0], acc[r]);   // v_fma_mix_f32
                    acc[r] = fmaf((float)v1[p][r], w[1], acc[r]);
                }
            }
        }
#pragma unroll
        for (int j = 0; j < 8; j++) acc[j] += __shfl_xor(acc[j], 4);

        if (xc == 0) {
            s16x8 o = pack8(make_float4(acc[0], acc[1], acc[2], acc[3]),
                            make_float4(acc[4], acc[5], acc[6], acc[7]));
            *(s16x8*)(sampled + (size_t)(qbase + q) * 256 + H * 32 + d8 * 8) = o;
        }
    }
}

// ---------------------------------------------------------------------------
extern "C" void kernel_launch(void* const* d_in, const int* in_sizes, int n_in,
                              void* d_out, int out_size, void* d_ws, size_t ws_size,
                              hipStream_t stream) {
    const float* query  = (const float*)d_in[0];
    const float* refpts = (const float*)d_in[1];
    const float* input_flatten = (const float*)d_in[2];
    const float* W_off  = (const float*)d_in[5];
    const float* b_off  = (const float*)d_in[6];
    const float* W_attn = (const float*)d_in[7];
    const float* b_attn = (const float*)d_in[8];
    const float* W_val  = (const float*)d_in[9];
    const float* b_val  = (const float*)d_in[10];
    const float* W_out  = (const float*)d_in[11];
    const float* b_out  = (const float*)d_in[12];
    float* out = (float*)d_out;

    char* ws = (char*)d_ws;
    f16*            value_t = (f16*)ws;                                    // 8*Q*32 f16   = 11141120 B
    f16*            offattn = (f16*)(ws + 11141120);                       // Q*384 f16    = 16711680 B
    unsigned short* sampled = (unsigned short*)(ws + 27852800);            // Q*256 bf16   = 11141120 B

    // value_t + offattn in one dispatch (weights converted in-kernel)
    gemm_fused<<<dim3(170, 5), 256, 0, stream>>>(input_flatten, query,
                                                 W_val, b_val, W_off, b_off, W_attn, b_attn,
                                                 value_t, offattn);
    // bilinear sampling + attention-weighted sum
    sample_kernel<<<dim3((Q_TOTAL / QB) * 4), 256, 0, stream>>>(value_t, offattn, refpts, sampled);
    // out = sampled @ W_out^T + b_out
    gemm_out<<<dim3(170, 2), 256, 0, stream>>>(sampled, W_out, b_out, out);
}